// Round 5
// baseline (1370.228 us; speedup 1.0000x reference)
//
#include <hip/hip_runtime.h>
#include <cstdint>

typedef long long ll;
typedef __bf16 bf16x8 __attribute__((ext_vector_type(8)));
typedef float f32x4 __attribute__((ext_vector_type(4)));
typedef unsigned int u32x4 __attribute__((ext_vector_type(4)));

#define NB 8
#define NT 12
#define NF 64
#define HWSZ 4096

struct alignas(8)  bh4 { __bf16 h[4]; };
struct alignas(16) bh8 { __bf16 h[8]; };

static __device__ inline f32x4 mfma16(bf16x8 a, bf16x8 b, f32x4 c) {
  return __builtin_amdgcn_mfma_f32_16x16x32_bf16(a, b, c, 0, 0, 0);
}
static __device__ inline bf16x8 ld8(const __bf16* p) {
  u32x4 u = *(const u32x4*)p;
  return __builtin_bit_cast(bf16x8, u);
}
static __device__ inline void st4(__bf16* p, float a0, float a1, float a2, float a3) {
  bh4 t; t.h[0] = (__bf16)a0; t.h[1] = (__bf16)a1; t.h[2] = (__bf16)a2; t.h[3] = (__bf16)a3;
  *(bh4*)p = t;
}
static __device__ inline float lky(float a) { return a >= 0.f ? a : 0.2f * a; }

// XCD-chunked swizzle (grid divisible by 8): neighbors share an XCD L2.
static __device__ inline int swz_bid() {
  int bid = blockIdx.x;
  return ((gridDim.x & 7) == 0) ? (bid & 7) * (gridDim.x >> 3) + (bid >> 3) : bid;
}

// Stage one row, HALF the channels (granules goff..goff+3) into [g4][W][8].
template<int W, int HALO>
static __device__ void stage_half(__bf16* dst, const __bf16* grow, int goff) {
  int tid = threadIdx.x;
  u32x4 zz = {0u, 0u, 0u, 0u};
  {
    int xr = tid >> 2, g = tid & 3, xi = xr + HALO;
    u32x4 v = zz;
    if (grow) v = *(const u32x4*)(grow + xr * 64 + (goff + g) * 8);
    *(u32x4*)(dst + (g * W + xi) * 8) = v;
  }
  if (tid < 8 * HALO) {
    int h = tid >> 2, g = tid & 3;
    int xi = (h < HALO) ? h : 64 + h;
    *(u32x4*)(dst + (g * W + xi) * 8) = zz;
  }
}

// Stage one row of a 32-ch NHWC bf16 map into [g4][W][8].
template<int W, int HALO>
static __device__ void stage4(__bf16* dst, const __bf16* grow) {
  int tid = threadIdx.x;
  u32x4 zz = {0u, 0u, 0u, 0u};
  {
    int xr = tid >> 2, g = tid & 3, xi = xr + HALO;
    u32x4 v = zz;
    if (grow) v = *(const u32x4*)(grow + xr * 32 + g * 8);
    *(u32x4*)(dst + (g * W + xi) * 8) = v;
  }
  if (tid < 8 * HALO) {
    int h = tid >> 2, g = tid & 3;
    int xi = (h < HALO) ? h : 64 + h;
    *(u32x4*)(dst + (g * W + xi) * 8) = zz;
  }
}

// ---------------------------------------------------------------------------
// Weight pre-transform: bf16 fragment-friendly layouts.
__global__ __launch_bounds__(256) void k_prep(
    const float* __restrict__ Wd, const float* __restrict__ Wc,
    const float* __restrict__ Wi, const float* __restrict__ Wh,
    const float* __restrict__ Wfl, const float* __restrict__ Wret,
    __bf16* __restrict__ Adown, __bf16* __restrict__ Ai2h,
    __bf16* __restrict__ Afi, __bf16* __restrict__ Afh,
    __bf16* __restrict__ Afl, __bf16* __restrict__ Aret) {
  int n = blockIdx.x * 256 + threadIdx.x;
  if (n < 147456) {                            // Adown[oc][k]
    Adown[n] = (__bf16)Wd[n];
  } else if (n < 258048) {                     // Ai2h[tap][o192][c64]
    int i = n - 147456;
    int tap = i / 12288, o = (i % 12288) / 64, c = i % 64;
    Ai2h[i] = (__bf16)Wc[(o * 64 + c) * 9 + tap];
  } else if (n < 309248) {                     // Afi[tap][o32][c64]
    int i = n - 258048;
    int tap = i / 2048, o = (i % 2048) / 64, c = i % 64;
    Afi[i] = (__bf16)Wi[(o * 64 + c) * 25 + tap];
  } else if (n < 360448) {                     // Afh[tap][o32][c64]
    int i = n - 309248;
    int tap = i / 2048, o = (i % 2048) / 64, c = i % 64;
    Afh[i] = (__bf16)Wh[(o * 64 + c) * 25 + tap];
  } else if (n < 373248) {                     // Afl[tap][o16 pad][c32]
    int i = n - 360448;
    int tap = i / 512, o = (i % 512) / 32, c = i % 32;
    Afl[i] = (__bf16)(o < 10 ? Wfl[(o * 32 + c) * 25 + tap] : 0.f);
  } else if (n < 434688) {                     // Aret[o192][c320]
    Aret[n - 373248] = (__bf16)Wret[n - 373248];
  }
}

// ---------------------------------------------------------------------------
// Downsample conv as MFMA implicit GEMM. (b,y,zQ); zQ splits M=768 into 4.
__global__ __launch_bounds__(256) void k_down(
    const float* __restrict__ x, const __bf16* __restrict__ Adown,
    const float* __restrict__ bd, __bf16* __restrict__ seq) {
  __shared__ __bf16 smd[6240];
  int bi = swz_bid();
  int zQ = bi & 3, y = (bi >> 2) & 63, b = bi >> 8;
  int tid = threadIdx.x;
  for (int i = tid; i < 6240; i += 256) {
    int ic = i / 520, rem = i % 520, ky = rem / 130, xi = rem % 130;
    int ix = xi - 1, iy = 2 * y - 1 + ky;
    float v = (ix >= 0 && ix < 128 && iy >= 0 && iy < 128)
                  ? x[(((ll)(b * 12 + ic) * 128 + iy) << 7) + ix] : 0.f;
    smd[i] = (__bf16)v;
  }
  __syncthreads();
  int wv = __builtin_amdgcn_readfirstlane(tid >> 6);
  int lane = tid & 63, q = lane >> 4, lr = lane & 15;
  int px = wv * 16 + lr;
  f32x4 zv = {0.f, 0.f, 0.f, 0.f};
  f32x4 acc[12];
  #pragma unroll
  for (int mt = 0; mt < 12; ++mt) acc[mt] = zv;

  for (int ks = 0; ks < 6; ++ks) {
    int k0 = ks * 32 + q * 8;
    int ic = k0 >> 4, ky0 = (k0 >> 2) & 3;
    const __bf16* rp = smd + (ic * 4 + ky0) * 130 + 2 * px;
    bh8 bb;
    #pragma unroll
    for (int j = 0; j < 8; ++j)
      bb.h[j] = rp[(j >> 2) * 130 + (j & 3)];
    bf16x8 bfr = __builtin_bit_cast(bf16x8, bb);
    #pragma unroll
    for (int mt = 0; mt < 12; ++mt) {
      bf16x8 afr = ld8(Adown + ((ll)(zQ * 192 + mt * 16 + lr) * 192 + k0));
      acc[mt] = mfma16(afr, bfr, acc[mt]);
    }
  }
  #pragma unroll
  for (int mt = 0; mt < 12; ++mt) {
    int t_idx = zQ * 3 + (mt >> 2);
    int f0 = (mt & 3) * 16 + q * 4;
    float v[4];
    #pragma unroll
    for (int r = 0; r < 4; ++r)
      v[r] = lky(acc[mt][r] + bd[zQ * 192 + mt * 16 + q * 4 + r]);
    st4(seq + (((ll)(t_idx * NB + b) * 4096 + y * 64 + px) * 64 + f0),
        v[0], v[1], v[2], v[3]);
  }
}

// ---------------------------------------------------------------------------
// i2h 3x3 conv: block = (tb, ypair, oc-half): 2 rows x 64 px x 96 oc.
// Wave (mh, xh): 3 mt x 2 nx x 2 r = 12 acc tiles (48 AGPR). ks-split
// double-pass staging keeps LDS at 17.2 KB. A-prefetch 1-deep only.
__global__ __launch_bounds__(256, 3) void k_i2h3(
    const __bf16* __restrict__ in0, const __bf16* __restrict__ A,
    const float* __restrict__ bc, __bf16* __restrict__ out0) {
  __shared__ __align__(16) __bf16 sm[4 * 4 * 67 * 8];
  int bi_ = swz_bid();
  int och = bi_ & 1, yp = (bi_ >> 1) & 31, tb = bi_ >> 6;
  int y0 = yp * 2;
  const __bf16* base = in0 + (ll)tb * (4096 * 64);
  int tid = threadIdx.x;
  int wv = __builtin_amdgcn_readfirstlane(tid >> 6);
  int lane = tid & 63, q = lane >> 4, lr = lane & 15;
  int mh = wv & 1, xh = wv >> 1;
  f32x4 zv = {0.f, 0.f, 0.f, 0.f};
  f32x4 acc[3][2][2];
  #pragma unroll
  for (int mt = 0; mt < 3; ++mt)
    #pragma unroll
    for (int nx = 0; nx < 2; ++nx)
      #pragma unroll
      for (int r = 0; r < 2; ++r) acc[mt][nx][r] = zv;

  int obase = och * 96 + mh * 48;        // oc base for this wave
  bf16x8 ca[3], na[3];
  auto loadA = [&](int tap, int ks, bf16x8* aa) {
    #pragma unroll
    for (int mt = 0; mt < 3; ++mt)
      aa[mt] = ld8(A + ((ll)(tap * 192 + obase + mt * 16 + lr) * 64 +
                        ks * 32 + q * 8));
  };

  #pragma unroll
  for (int ks = 0; ks < 2; ++ks) {
    if (ks) __syncthreads();
    #pragma unroll
    for (int s = 0; s < 4; ++s) {
      int yr = y0 - 1 + s;
      stage_half<67, 1>(sm + s * (4 * 67 * 8),
                        (yr >= 0 && yr < 64) ? base + (ll)yr * 64 * 64 : nullptr,
                        ks * 4);
    }
    __syncthreads();
    loadA(0, ks, ca);
    #pragma unroll
    for (int tap = 0; tap < 9; ++tap) {
      if (tap < 8) loadA(tap + 1, ks, na);
      int ky = tap / 3, kx = tap % 3;
      bf16x8 bb[2][2];
      #pragma unroll
      for (int nx = 0; nx < 2; ++nx)
        #pragma unroll
        for (int r = 0; r < 2; ++r)
          bb[nx][r] = ld8(sm + (((r + ky) * 4 + q) * 67 +
                                xh * 32 + nx * 16 + lr + kx) * 8);
      #pragma unroll
      for (int mt = 0; mt < 3; ++mt)
        #pragma unroll
        for (int nx = 0; nx < 2; ++nx)
          #pragma unroll
          for (int r = 0; r < 2; ++r)
            acc[mt][nx][r] = mfma16(ca[mt], bb[nx][r], acc[mt][nx][r]);
      ca[0] = na[0]; ca[1] = na[1]; ca[2] = na[2];
    }
  }

  #pragma unroll
  for (int nx = 0; nx < 2; ++nx) {
    int px = xh * 32 + nx * 16 + lr;
    #pragma unroll
    for (int r = 0; r < 2; ++r) {
      __bf16* op = out0 + ((ll)tb * 4096 + (y0 + r) * 64 + px) * 192;
      #pragma unroll
      for (int mt = 0; mt < 3; ++mt) {
        int oc0 = obase + mt * 16 + q * 4;
        st4(op + oc0, acc[mt][nx][r][0] + bc[oc0],
                      acc[mt][nx][r][1] + bc[oc0 + 1],
                      acc[mt][nx][r][2] + bc[oc0 + 2],
                      acc[mt][nx][r][3] + bc[oc0 + 3]);
      }
    }
  }
}

// ---------------------------------------------------------------------------
// Batched i2f 5x5 conv (no bias). 4 rows/block, wave = px-quarter x 4 rows x
// 2 mt (32 AGPR). ks-split double-pass; A-prefetch only. (256,4).
__global__ __launch_bounds__(256, 4) void k_conv5b(
    const __bf16* __restrict__ in0, const __bf16* __restrict__ A,
    __bf16* __restrict__ out0) {
  __shared__ __align__(16) __bf16 sm[8 * 4 * 69 * 8];
  int bi_ = swz_bid();
  int yg = bi_ & 15, tb = bi_ >> 4;
  int y0 = yg * 4;
  const __bf16* base = in0 + (ll)tb * (4096 * 64);
  int tid = threadIdx.x;
  int wv = __builtin_amdgcn_readfirstlane(tid >> 6);
  int lane = tid & 63, q = lane >> 4, lr = lane & 15;
  int px = wv * 16 + lr;
  f32x4 zv = {0.f, 0.f, 0.f, 0.f};
  f32x4 acc[2][4];
  #pragma unroll
  for (int mt = 0; mt < 2; ++mt)
    #pragma unroll
    for (int r = 0; r < 4; ++r) acc[mt][r] = zv;

  bf16x8 ca[2], na[2];
  auto loadA = [&](int tap, int ks, bf16x8* aa) {
    #pragma unroll
    for (int mt = 0; mt < 2; ++mt)
      aa[mt] = ld8(A + ((ll)(tap * 32 + mt * 16 + lr) * 64 + ks * 32 + q * 8));
  };

  #pragma unroll
  for (int ks = 0; ks < 2; ++ks) {
    if (ks) __syncthreads();
    #pragma unroll
    for (int s = 0; s < 8; ++s) {
      int yr = y0 - 2 + s;
      stage_half<69, 2>(sm + s * (4 * 69 * 8),
                        (yr >= 0 && yr < 64) ? base + (ll)yr * 64 * 64 : nullptr,
                        ks * 4);
    }
    __syncthreads();
    loadA(0, ks, ca);
    #pragma unroll
    for (int tap = 0; tap < 25; ++tap) {
      if (tap < 24) loadA(tap + 1, ks, na);
      int ky = tap / 5, kx = tap % 5;
      bf16x8 bb[4];
      #pragma unroll
      for (int r = 0; r < 4; ++r)
        bb[r] = ld8(sm + (((r + ky) * 4 + q) * 69 + px + kx) * 8);
      #pragma unroll
      for (int mt = 0; mt < 2; ++mt)
        #pragma unroll
        for (int r = 0; r < 4; ++r)
          acc[mt][r] = mfma16(ca[mt], bb[r], acc[mt][r]);
      ca[0] = na[0]; ca[1] = na[1];
    }
  }

  #pragma unroll
  for (int r = 0; r < 4; ++r) {
    __bf16* op = out0 + ((ll)tb * 4096 + (y0 + r) * 64 + px) * 32;
    #pragma unroll
    for (int mt = 0; mt < 2; ++mt) {
      int oc0 = mt * 16 + q * 4;
      st4(op + oc0, acc[mt][r][0], acc[mt][r][1], acc[mt][r][2], acc[mt][r][3]);
    }
  }
}

// ---------------------------------------------------------------------------
// Per-step f1 = leaky(i2f_t + bi + h2f(h) + bh). Block = (b, ypair, xhalf):
// 2 rows x 32 px. Single-pass 64-ch LDS [6][8][37][8] = 28.4 KB. Grid 512.
__global__ __launch_bounds__(256, 4) void k_h2f(
    const __bf16* __restrict__ hb, const __bf16* __restrict__ A,
    const float* __restrict__ bi, const float* __restrict__ bh,
    const __bf16* __restrict__ i2f_t, __bf16* __restrict__ f1buf) {
  __shared__ __align__(16) __bf16 sm[6 * 8 * 37 * 8];
  int bi_ = swz_bid();
  int xh = bi_ & 1, yg = (bi_ >> 1) & 31, b = bi_ >> 6;
  int y0 = yg * 2, x0 = xh * 32;
  int tid = threadIdx.x;
  u32x4 zz = {0u, 0u, 0u, 0u};
  for (int i = tid; i < 6 * 288; i += 256) {
    int s = i / 288, rem = i % 288, xi = rem >> 3, g = rem & 7;
    int yr = y0 - 2 + s, xg = x0 - 2 + xi;
    u32x4 v = zz;
    if (yr >= 0 && yr < 64 && xg >= 0 && xg < 64)
      v = *(const u32x4*)(hb + ((ll)(b * 64 + yr) * 64 + xg) * 64 + g * 8);
    *(u32x4*)(sm + ((s * 8 + g) * 37 + xi) * 8) = v;
  }
  __syncthreads();
  int wv = __builtin_amdgcn_readfirstlane(tid >> 6);
  int lane = tid & 63, q = lane >> 4, lr = lane & 15;
  int nt = wv & 1, r = wv >> 1;
  int pxl = nt * 16 + lr;
  f32x4 zv = {0.f, 0.f, 0.f, 0.f};
  f32x4 acc[2] = {zv, zv};
  bf16x8 ca[2], na[2];
  auto loadA = [&](int kk, bf16x8* aa) {
    int tap = kk >> 1, ks = kk & 1;
    #pragma unroll
    for (int mt = 0; mt < 2; ++mt)
      aa[mt] = ld8(A + ((ll)(tap * 32 + mt * 16 + lr) * 64 + ks * 32 + q * 8));
  };
  loadA(0, ca);
  #pragma unroll
  for (int kk = 0; kk < 50; ++kk) {
    if (kk < 49) loadA(kk + 1, na);
    int tap = kk >> 1, ks = kk & 1;
    int ky = tap / 5, kx = tap % 5;
    bf16x8 bfr = ld8(sm + (((r + ky) * 8 + ks * 4 + q) * 37 + pxl + kx) * 8);
    #pragma unroll
    for (int mt = 0; mt < 2; ++mt)
      acc[mt] = mfma16(ca[mt], bfr, acc[mt]);
    ca[0] = na[0]; ca[1] = na[1];
  }
  int y = y0 + r, px = x0 + pxl;
  const __bf16* ip = i2f_t + ((ll)(b * 64 + y) * 64 + px) * 32;
  __bf16* op = f1buf + ((ll)(b * 64 + y) * 64 + px) * 32;
  #pragma unroll
  for (int mt = 0; mt < 2; ++mt) {
    int oc0 = mt * 16 + q * 4;
    bh4 iv = *(const bh4*)(ip + oc0);
    float v[4];
    #pragma unroll
    for (int rr = 0; rr < 4; ++rr)
      v[rr] = lky(acc[mt][rr] + (float)iv.h[rr] + bi[oc0 + rr] + bh[oc0 + rr]);
    st4(op + oc0, v[0], v[1], v[2], v[3]);
  }
}

// ---------------------------------------------------------------------------
// Per-step fused: flow conv -> bilinear warp -> ret 1x1 GEMM -> GRU gates.
// LDS: pool (f1 stage 22 KB, later reused as warped 41 KB) + flows 4.3 KB.
// Warped layout [px64][G40][8] with G-low3 XOR px-swizzle.
__global__ __launch_bounds__(256, 3) void k_fwr(
    const __bf16* __restrict__ f1buf, const __bf16* __restrict__ Afl,
    const float* __restrict__ bfl, const __bf16* __restrict__ hb,
    const __bf16* __restrict__ Aret, const float* __restrict__ br,
    const __bf16* __restrict__ i2h_t, const float* __restrict__ hprevf,
    int t0, float* __restrict__ outp, ll osb, __bf16* __restrict__ hbc) {
  __shared__ __align__(16) __bf16 pool[64 * 40 * 8];   // 40960 B
  __shared__ float flows[64 * 17];                     //  4352 B
  __bf16* f1l = pool;                                  // [5][4][69][8] phase1-2
  __bf16* wrp = pool;                                  // [64][40][8]  phase3-4

  int bi = swz_bid();
  int y = bi & 63, b = bi >> 6;
  int tid = threadIdx.x;
  int wv = __builtin_amdgcn_readfirstlane(tid >> 6);
  int lane = tid & 63, q = lane >> 4, lr = lane & 15;
  int px = wv * 16 + lr;

  // phase 1: stage f1 rows y-2..y+2
  #pragma unroll
  for (int r = 0; r < 5; ++r) {
    int yr = y - 2 + r;
    stage4<69, 2>(f1l + r * (4 * 69 * 8),
                  (yr >= 0 && yr < 64) ? f1buf + ((ll)(b * 64 + yr) * 64) * 32 : nullptr);
  }
  __syncthreads();

  // phase 2: flow conv (M=16, 10 used; K=25x32)
  f32x4 acc1 = {0.f, 0.f, 0.f, 0.f};
  #pragma unroll
  for (int tap = 0; tap < 25; ++tap) {
    int ky = tap / 5, kx = tap % 5;
    bf16x8 bfr = ld8(f1l + (((ky * 4 + q) * 69) + px + kx) * 8);
    bf16x8 afr = ld8(Afl + ((ll)(tap * 16 + lr) * 32 + q * 8));
    acc1 = mfma16(afr, bfr, acc1);
  }
  __syncthreads();  // f1l reads done (pool free), flows not yet visible
  #pragma unroll
  for (int r = 0; r < 4; ++r) {
    int oc = q * 4 + r;
    flows[px * 17 + oc] = acc1[r] + (oc < 10 ? bfl[oc] : 0.f);
  }
  __syncthreads();

  // phase 3: warp 5 trajectories into wrp [px][G][8], G-swizzled
  {
    int xw = tid & 63, cg = tid >> 6;
    const __bf16* hbb = hb + ((ll)b << 18);
    #pragma unroll
    for (int l = 0; l < 5; ++l) {
      float fx = flows[xw * 17 + 2 * l];
      float fy = flows[xw * 17 + 2 * l + 1];
      float pxf = (float)xw - fx, pyf = (float)y - fy;
      float x0f = floorf(pxf), y0f = floorf(pyf);
      int x0 = (int)x0f, y0 = (int)y0f, x1 = x0 + 1, y1 = y0 + 1;
      float dx = pxf - x0f, dy = pyf - y0f;
      bool vx0 = x0 >= 0 && x0 <= 63, vx1 = x1 >= 0 && x1 <= 63;
      bool vy0 = y0 >= 0 && y0 <= 63, vy1 = y1 >= 0 && y1 <= 63;
      float wA = (vx0 && vy0) ? (1.f - dx) * (1.f - dy) : 0.f;
      float wB = (vx0 && vy1) ? (1.f - dx) * dy : 0.f;
      float wC = (vx1 && vy0) ? dx * (1.f - dy) : 0.f;
      float wD = (vx1 && vy1) ? dx * dy : 0.f;
      int cx0 = min(max(x0, 0), 63), cx1 = min(max(x1, 0), 63);
      int cy0 = min(max(y0, 0), 63), cy1 = min(max(y1, 0), 63);
      int o00 = (cy0 * 64 + cx0) * 64, o10 = (cy1 * 64 + cx0) * 64;
      int o01 = (cy0 * 64 + cx1) * 64, o11 = (cy1 * 64 + cx1) * 64;
      #pragma unroll
      for (int it = 0; it < 2; ++it) {
        int cgp = cg + it * 4;
        int c0 = cgp * 8;
        bf16x8 aA = ld8(hbb + o00 + c0), aB = ld8(hbb + o10 + c0);
        bf16x8 aC = ld8(hbb + o01 + c0), aD = ld8(hbb + o11 + c0);
        bh8 ov;
        #pragma unroll
        for (int i = 0; i < 8; ++i)
          ov.h[i] = (__bf16)(wA * (float)aA[i] + wB * (float)aB[i] +
                             wC * (float)aC[i] + wD * (float)aD[i]);
        int G = l * 8 + cgp;
        int Gs = (G & ~7) | ((G & 7) ^ (xw & 7));
        *(bh8*)(wrp + (xw * 40 + Gs) * 8) = ov;
      }
    }
  }
  __syncthreads();

  // phase 4: ret 1x1 GEMM (M=192, K=320)
  f32x4 zv = {0.f, 0.f, 0.f, 0.f};
  f32x4 acc[12];
  #pragma unroll
  for (int mt = 0; mt < 12; ++mt) acc[mt] = zv;
  #pragma unroll
  for (int ks = 0; ks < 10; ++ks) {
    int Gr = ks * 4 + q;
    int Gs = (Gr & ~7) | ((Gr & 7) ^ (px & 7));
    bf16x8 bfr = ld8(wrp + (px * 40 + Gs) * 8);
    #pragma unroll
    for (int mt = 0; mt < 12; ++mt) {
      bf16x8 afr = ld8(Aret + ((ll)(mt * 16 + lr) * 320 + ks * 32 + q * 8));
      acc[mt] = mfma16(afr, bfr, acc[mt]);
    }
  }

  // phase 5: gates
  const __bf16* ih = i2h_t + ((ll)(b * 64 + y) * 64 + px) * 192;
  const float* hp = hprevf + (ll)b * osb + y * 64 + px;
  float* ob = outp + (ll)b * osb + y * 64 + px;
  __bf16* hc = hbc + ((ll)(b * 64 + y) * 64 + px) * 64;
  #pragma unroll
  for (int ft = 0; ft < 4; ++ft) {
    int f0 = ft * 16 + q * 4;
    bh4 irv = *(const bh4*)(ih + f0);
    bh4 iuv = *(const bh4*)(ih + f0 + 64);
    bh4 imv = *(const bh4*)(ih + f0 + 128);
    float hn4[4];
    #pragma unroll
    for (int r = 0; r < 4; ++r) {
      int f = f0 + r;
      float hr = acc[ft][r] + br[f];
      float hu = acc[ft + 4][r] + br[f + 64];
      float hm = acc[ft + 8][r] + br[f + 128];
      float rr = 1.f / (1.f + __expf(-((float)irv.h[r] + hr)));
      float uu = 1.f / (1.f + __expf(-((float)iuv.h[r] + hu)));
      float m = lky((float)imv.h[r] + rr * hm);
      float h0 = t0 ? 0.f : hp[(ll)f << 12];
      float hn = uu * h0 + (1.f - uu) * m;
      ob[(ll)f << 12] = hn;
      hn4[r] = hn;
    }
    st4(hc + f0, hn4[0], hn4[1], hn4[2], hn4[3]);
  }
}

// ---------------------------------------------------------------------------
extern "C" void kernel_launch(void* const* d_in, const int* in_sizes, int n_in,
                              void* d_out, int out_size, void* d_ws, size_t ws_size,
                              hipStream_t stream) {
  const float* x      = (const float*)d_in[0];
  const float* W_down = (const float*)d_in[1];
  const float* b_down = (const float*)d_in[2];
  const float* W_i2h  = (const float*)d_in[3];
  const float* b_i2h  = (const float*)d_in[4];
  const float* W_i2f  = (const float*)d_in[5];
  const float* b_i2f  = (const float*)d_in[6];
  const float* W_h2f  = (const float*)d_in[7];
  const float* b_h2f  = (const float*)d_in[8];
  const float* W_flow = (const float*)d_in[9];
  const float* b_flow = (const float*)d_in[10];
  const float* W_ret  = (const float*)d_in[11];
  const float* b_ret  = (const float*)d_in[12];
  float* out = (float*)d_out;

  const ll I2H_T = (ll)NB * 4096 * 192;
  const ll I2F_T = (ll)NB * 4096 * 32;
  const ll H_N   = (ll)NB * 4096 * 64;

  auto align256 = [](ll v) { return (v + 255) & ~255LL; };
  ll fixed = 0;
  fixed += align256(147456LL * 2);
  fixed += align256(110592LL * 2);
  fixed += align256(51200LL * 2);
  fixed += align256(51200LL * 2);
  fixed += align256(12800LL * 2);
  fixed += align256(61440LL * 2);
  fixed += align256((ll)NT * NB * 4096 * 64 * 2);
  fixed += align256((ll)NB * 4096 * 32 * 2);
  fixed += align256(H_N * 2) * 3;
  ll need_full = fixed + align256(NT * I2H_T * 2) + align256(NT * I2F_T * 2);
  int fits = (need_full <= (ll)ws_size);
  int slabT = fits ? NT : 1;

  char* p = (char*)d_ws;
  auto alloc = [&](ll bytes) { char* r = p; p += (bytes + 255) & ~255LL; return r; };
  __bf16* Adown  = (__bf16*)alloc(147456LL * 2);
  __bf16* Ai2h   = (__bf16*)alloc(110592LL * 2);
  __bf16* Afi    = (__bf16*)alloc(51200LL * 2);
  __bf16* Afh    = (__bf16*)alloc(51200LL * 2);
  __bf16* Afl    = (__bf16*)alloc(12800LL * 2);
  __bf16* Aret   = (__bf16*)alloc(61440LL * 2);
  __bf16* seq    = (__bf16*)alloc((ll)NT * NB * 4096 * 64 * 2);
  __bf16* f1buf  = (__bf16*)alloc((ll)NB * 4096 * 32 * 2);
  __bf16* hzb    = (__bf16*)alloc(H_N * 2);
  __bf16* hbufA  = (__bf16*)alloc(H_N * 2);
  __bf16* hbufB  = (__bf16*)alloc(H_N * 2);
  __bf16* i2h_sl = (__bf16*)alloc(slabT * I2H_T * 2);
  __bf16* i2f_sl = (__bf16*)alloc(slabT * I2F_T * 2);
  if (p > (char*)d_ws + ws_size) return;

  hipMemsetAsync(hzb, 0, (size_t)H_N * 2, stream);

  k_prep<<<1698, 256, 0, stream>>>(W_down, W_i2h, W_i2f, W_h2f, W_flow, W_ret,
                                   Adown, Ai2h, Afi, Afh, Afl, Aret);
  k_down<<<NB * 64 * 4, 256, 0, stream>>>(x, Adown, b_down, seq);

  if (fits) {
    k_i2h3<<<NT * NB * 64, 256, 0, stream>>>(seq, Ai2h, b_i2h, i2h_sl);
    k_conv5b<<<NT * NB * 16, 256, 0, stream>>>(seq, Afi, i2f_sl);
  }

  const ll osb = (ll)NT * NF * HWSZ;
  for (int t = 0; t < NT; ++t) {
    const __bf16* xt0 = seq + (ll)t * NB * 4096 * 64;
    if (!fits) {
      k_i2h3<<<NB * 64, 256, 0, stream>>>(xt0, Ai2h, b_i2h, i2h_sl);
      k_conv5b<<<NB * 16, 256, 0, stream>>>(xt0, Afi, i2f_sl);
    }
    int ti = fits ? t : 0;
    const __bf16* hb = (t == 0) ? hzb : ((t & 1) ? hbufA : hbufB);
    __bf16* hbc = (t & 1) ? hbufB : hbufA;
    const float* hpf = (t == 0) ? out : out + (ll)(t - 1) * NF * HWSZ;

    k_h2f<<<NB * 64, 256, 0, stream>>>(hb, Afh, b_i2f, b_h2f,
                                       i2f_sl + (ll)ti * I2F_T, f1buf);
    k_fwr<<<NB * 64, 256, 0, stream>>>(f1buf, Afl, b_flow, hb, Aret, b_ret,
                                       i2h_sl + (ll)ti * I2H_T, hpf,
                                       (t == 0) ? 1 : 0,
                                       out + (ll)t * NF * HWSZ, osb, hbc);
  }
}

// Round 6
// 978.776 us; speedup vs baseline: 1.3999x; 1.3999x over previous
//
#include <hip/hip_runtime.h>
#include <cstdint>

typedef long long ll;
typedef __bf16 bf16x8 __attribute__((ext_vector_type(8)));
typedef float f32x4 __attribute__((ext_vector_type(4)));
typedef unsigned int u32x4 __attribute__((ext_vector_type(4)));

#define NB 8
#define NT 12
#define NF 64
#define HWSZ 4096

struct alignas(8)  bh4 { __bf16 h[4]; };
struct alignas(16) bh8 { __bf16 h[8]; };

static __device__ inline f32x4 mfma16(bf16x8 a, bf16x8 b, f32x4 c) {
  return __builtin_amdgcn_mfma_f32_16x16x32_bf16(a, b, c, 0, 0, 0);
}
static __device__ inline bf16x8 ld8(const __bf16* p) {
  u32x4 u = *(const u32x4*)p;
  return __builtin_bit_cast(bf16x8, u);
}
static __device__ inline void st4(__bf16* p, float a0, float a1, float a2, float a3) {
  bh4 t; t.h[0] = (__bf16)a0; t.h[1] = (__bf16)a1; t.h[2] = (__bf16)a2; t.h[3] = (__bf16)a3;
  *(bh4*)p = t;
}
static __device__ inline float lky(float a) { return a >= 0.f ? a : 0.2f * a; }

// XCD-chunked swizzle (grid divisible by 8): neighbors share an XCD L2.
static __device__ inline int swz_bid() {
  int bid = blockIdx.x;
  return ((gridDim.x & 7) == 0) ? (bid & 7) * (gridDim.x >> 3) + (bid >> 3) : bid;
}

// Stage one row of a 64-ch NHWC bf16 map into LDS [g8][W][8] (full channels).
template<int W, int HALO>
static __device__ void stage8(__bf16* dst, const __bf16* grow) {
  int tid = threadIdx.x;
  u32x4 zz = {0u, 0u, 0u, 0u};
  #pragma unroll
  for (int it = 0; it < 2; ++it) {
    int i = tid + it * 256;
    int xr = i >> 3, g = i & 7, xi = xr + HALO;
    u32x4 v = zz;
    if (grow) v = *(const u32x4*)(grow + xr * 64 + g * 8);
    *(u32x4*)(dst + (g * W + xi) * 8) = v;
  }
  if (tid < 16 * HALO) {
    int h = tid >> 3, g = tid & 7;
    int xi = (h < HALO) ? h : 64 + h;
    *(u32x4*)(dst + (g * W + xi) * 8) = zz;
  }
}

// Stage one row of a 32-ch NHWC bf16 map into [g4][W][8].
template<int W, int HALO>
static __device__ void stage4(__bf16* dst, const __bf16* grow) {
  int tid = threadIdx.x;
  u32x4 zz = {0u, 0u, 0u, 0u};
  {
    int xr = tid >> 2, g = tid & 3, xi = xr + HALO;
    u32x4 v = zz;
    if (grow) v = *(const u32x4*)(grow + xr * 32 + g * 8);
    *(u32x4*)(dst + (g * W + xi) * 8) = v;
  }
  if (tid < 8 * HALO) {
    int h = tid >> 2, g = tid & 3;
    int xi = (h < HALO) ? h : 64 + h;
    *(u32x4*)(dst + (g * W + xi) * 8) = zz;
  }
}

// ---------------------------------------------------------------------------
// Weight pre-transform: bf16 fragment-friendly layouts.
__global__ __launch_bounds__(256) void k_prep(
    const float* __restrict__ Wd, const float* __restrict__ Wc,
    const float* __restrict__ Wi, const float* __restrict__ Wh,
    const float* __restrict__ Wfl, const float* __restrict__ Wret,
    __bf16* __restrict__ Adown, __bf16* __restrict__ Ai2h,
    __bf16* __restrict__ Afi, __bf16* __restrict__ Afh,
    __bf16* __restrict__ Afl, __bf16* __restrict__ Aret) {
  int n = blockIdx.x * 256 + threadIdx.x;
  if (n < 147456) {                            // Adown[oc][k]
    Adown[n] = (__bf16)Wd[n];
  } else if (n < 258048) {                     // Ai2h[tap][o192][c64]
    int i = n - 147456;
    int tap = i / 12288, o = (i % 12288) / 64, c = i % 64;
    Ai2h[i] = (__bf16)Wc[(o * 64 + c) * 9 + tap];
  } else if (n < 309248) {                     // Afi[tap][o32][c64]
    int i = n - 258048;
    int tap = i / 2048, o = (i % 2048) / 64, c = i % 64;
    Afi[i] = (__bf16)Wi[(o * 64 + c) * 25 + tap];
  } else if (n < 360448) {                     // Afh[tap][o32][c64]
    int i = n - 309248;
    int tap = i / 2048, o = (i % 2048) / 64, c = i % 64;
    Afh[i] = (__bf16)Wh[(o * 64 + c) * 25 + tap];
  } else if (n < 373248) {                     // Afl[tap][o16 pad][c32]
    int i = n - 360448;
    int tap = i / 512, o = (i % 512) / 32, c = i % 32;
    Afl[i] = (__bf16)(o < 10 ? Wfl[(o * 32 + c) * 25 + tap] : 0.f);
  } else if (n < 434688) {                     // Aret[o192][c320]
    Aret[n - 373248] = (__bf16)Wret[n - 373248];
  }
}

// ---------------------------------------------------------------------------
// Downsample conv as MFMA implicit GEMM. (b,y,zQ); zQ splits M=768 into 4.
__global__ __launch_bounds__(256) void k_down(
    const float* __restrict__ x, const __bf16* __restrict__ Adown,
    const float* __restrict__ bd, __bf16* __restrict__ seq) {
  __shared__ __bf16 smd[6240];
  int bi = swz_bid();
  int zQ = bi & 3, y = (bi >> 2) & 63, b = bi >> 8;
  int tid = threadIdx.x;
  for (int i = tid; i < 6240; i += 256) {
    int ic = i / 520, rem = i % 520, ky = rem / 130, xi = rem % 130;
    int ix = xi - 1, iy = 2 * y - 1 + ky;
    float v = (ix >= 0 && ix < 128 && iy >= 0 && iy < 128)
                  ? x[(((ll)(b * 12 + ic) * 128 + iy) << 7) + ix] : 0.f;
    smd[i] = (__bf16)v;
  }
  __syncthreads();
  int wv = __builtin_amdgcn_readfirstlane(tid >> 6);
  int lane = tid & 63, q = lane >> 4, lr = lane & 15;
  int px = wv * 16 + lr;
  f32x4 zv = {0.f, 0.f, 0.f, 0.f};
  f32x4 acc[12];
  #pragma unroll
  for (int mt = 0; mt < 12; ++mt) acc[mt] = zv;

  for (int ks = 0; ks < 6; ++ks) {
    int k0 = ks * 32 + q * 8;
    int ic = k0 >> 4, ky0 = (k0 >> 2) & 3;
    const __bf16* rp = smd + (ic * 4 + ky0) * 130 + 2 * px;
    bh8 bb;
    #pragma unroll
    for (int j = 0; j < 8; ++j)
      bb.h[j] = rp[(j >> 2) * 130 + (j & 3)];
    bf16x8 bfr = __builtin_bit_cast(bf16x8, bb);
    #pragma unroll
    for (int mt = 0; mt < 12; ++mt) {
      bf16x8 afr = ld8(Adown + ((ll)(zQ * 192 + mt * 16 + lr) * 192 + k0));
      acc[mt] = mfma16(afr, bfr, acc[mt]);
    }
  }
  #pragma unroll
  for (int mt = 0; mt < 12; ++mt) {
    int t_idx = zQ * 3 + (mt >> 2);
    int f0 = (mt & 3) * 16 + q * 4;
    float v[4];
    #pragma unroll
    for (int r = 0; r < 4; ++r)
      v[r] = lky(acc[mt][r] + bd[zQ * 192 + mt * 16 + q * 4 + r]);
    st4(seq + (((ll)(t_idx * NB + b) * 4096 + y * 64 + px) * 64 + f0),
        v[0], v[1], v[2], v[3]);
  }
}

// ---------------------------------------------------------------------------
// i2h 3x3 conv, A staged per-tap in double-buffered LDS (no global loads in
// the MFMA loop). Block = (tb, och, yg): 96 oc x 4 rows x 64 px.
// Wave (mh, rg): 3 mt x 8 nt (2 rows), acc 96 AGPR.
__global__ __launch_bounds__(256, 2) void k_i2h4(
    const __bf16* __restrict__ in0, const __bf16* __restrict__ A,
    const float* __restrict__ bc, __bf16* __restrict__ out0) {
  __shared__ __align__(16) __bf16 smI[6 * 8 * 67 * 8];   // 51456 B
  __shared__ __align__(16) __bf16 smA[2][96 * 64];       // 24576 B
  int bi_ = swz_bid();
  int yg = bi_ & 15, och = (bi_ >> 4) & 1, tb = bi_ >> 5;
  int y0 = yg * 4;
  const __bf16* base = in0 + (ll)tb * (4096 * 64);
  const __bf16* Ab = A + ((ll)och * 96) * 64;
  int tid = threadIdx.x;
  #pragma unroll
  for (int s = 0; s < 6; ++s) {
    int yr = y0 - 1 + s;
    stage8<67, 1>(smI + s * (8 * 67 * 8),
                  (yr >= 0 && yr < 64) ? base + (ll)yr * 64 * 64 : nullptr);
  }
  u32x4 ar[3];
  auto loadA = [&](int tap) {
    #pragma unroll
    for (int it = 0; it < 3; ++it) {
      int j = it * 256 + tid;
      ar[it] = *(const u32x4*)(Ab + (ll)tap * (192 * 64) + j * 8);
    }
  };
  auto writeA = [&](int buf) {
    #pragma unroll
    for (int it = 0; it < 3; ++it) {
      int j = it * 256 + tid;
      int oc = j >> 3, g = j & 7;
      *(u32x4*)(smA[buf] + oc * 64 + ((g ^ (oc & 7)) * 8)) = ar[it];
    }
  };
  loadA(0);
  writeA(0);
  __syncthreads();

  int wv = __builtin_amdgcn_readfirstlane(tid >> 6);
  int lane = tid & 63, q = lane >> 4, lr = lane & 15;
  int mh = wv & 1, rg = wv >> 1;
  f32x4 zv = {0.f, 0.f, 0.f, 0.f};
  f32x4 acc[3][8];
  #pragma unroll
  for (int mt = 0; mt < 3; ++mt)
    #pragma unroll
    for (int nt = 0; nt < 8; ++nt) acc[mt][nt] = zv;

  for (int tap = 0; tap < 9; ++tap) {
    if (tap < 8) loadA(tap + 1);            // issue early (T14)
    int ky = tap / 3, kx = tap % 3;
    const __bf16* Ax = smA[tap & 1];
    #pragma unroll
    for (int ks = 0; ks < 2; ++ks) {
      bf16x8 afr[3];
      #pragma unroll
      for (int mt = 0; mt < 3; ++mt) {
        int oc = mh * 48 + mt * 16 + lr;
        afr[mt] = ld8(Ax + oc * 64 + (((ks * 4 + q) ^ (lr & 7)) * 8));
      }
      bf16x8 bfr[8];
      #pragma unroll
      for (int rl = 0; rl < 2; ++rl)
        #pragma unroll
        for (int nx = 0; nx < 4; ++nx) {
          int s = rg * 2 + rl + ky;
          bfr[rl * 4 + nx] =
              ld8(smI + ((s * 8 + ks * 4 + q) * 67 + nx * 16 + lr + kx) * 8);
        }
      #pragma unroll
      for (int mt = 0; mt < 3; ++mt)
        #pragma unroll
        for (int nt = 0; nt < 8; ++nt)
          acc[mt][nt] = mfma16(afr[mt], bfr[nt], acc[mt][nt]);
    }
    if (tap < 8) writeA((tap + 1) & 1);     // write late
    __syncthreads();
  }

  #pragma unroll
  for (int rl = 0; rl < 2; ++rl)
    #pragma unroll
    for (int nx = 0; nx < 4; ++nx) {
      int row = y0 + rg * 2 + rl, px = nx * 16 + lr;
      __bf16* op = out0 + ((ll)tb * 4096 + row * 64 + px) * 192;
      #pragma unroll
      for (int mt = 0; mt < 3; ++mt) {
        int oc0 = och * 96 + mh * 48 + mt * 16 + q * 4;
        f32x4 a = acc[mt][rl * 4 + nx];
        st4(op + oc0, a[0] + bc[oc0], a[1] + bc[oc0 + 1],
                      a[2] + bc[oc0 + 2], a[3] + bc[oc0 + 3]);
      }
    }
}

// ---------------------------------------------------------------------------
// Batched i2f 5x5 (no bias). A per-tap in double-buffered LDS; K split across
// wave pairs (ksh) with f32 LDS reduction (reuses input region).
// Block = (tb, yg): 4 rows x 64 px x 32 oc. Wave (rg, ksh): 2 mt x 8 nt.
__global__ __launch_bounds__(256, 2) void k_i2fb(
    const __bf16* __restrict__ in0, const __bf16* __restrict__ A,
    __bf16* __restrict__ out0) {
  __shared__ __align__(16) __bf16 smI[8 * 8 * 69 * 8];   // 70656 B
  __shared__ __align__(16) __bf16 smA[2][32 * 64];       // 8192 B
  float* red = (float*)smI;                              // [4][64][33] later
  int bi_ = swz_bid();
  int yg = bi_ & 15, tb = bi_ >> 4;
  int y0 = yg * 4;
  const __bf16* base = in0 + (ll)tb * (4096 * 64);
  int tid = threadIdx.x;
  #pragma unroll
  for (int s = 0; s < 8; ++s) {
    int yr = y0 - 2 + s;
    stage8<69, 2>(smI + s * (8 * 69 * 8),
                  (yr >= 0 && yr < 64) ? base + (ll)yr * 64 * 64 : nullptr);
  }
  u32x4 ar;
  auto loadA = [&](int tap) { ar = *(const u32x4*)(A + (ll)tap * 2048 + tid * 8); };
  auto writeA = [&](int buf) {
    int oc = tid >> 3, g = tid & 7;
    *(u32x4*)(smA[buf] + oc * 64 + ((g ^ (oc & 7)) * 8)) = ar;
  };
  loadA(0);
  writeA(0);
  __syncthreads();

  int wv = __builtin_amdgcn_readfirstlane(tid >> 6);
  int lane = tid & 63, q = lane >> 4, lr = lane & 15;
  int rg = wv & 1, ksh = wv >> 1;
  f32x4 zv = {0.f, 0.f, 0.f, 0.f};
  f32x4 acc[2][8];
  #pragma unroll
  for (int mt = 0; mt < 2; ++mt)
    #pragma unroll
    for (int nt = 0; nt < 8; ++nt) acc[mt][nt] = zv;

  for (int tap = 0; tap < 25; ++tap) {
    if (tap < 24) loadA(tap + 1);
    int ky = tap / 5, kx = tap % 5;
    const __bf16* Ax = smA[tap & 1];
    bf16x8 afr[2];
    #pragma unroll
    for (int mt = 0; mt < 2; ++mt) {
      int oc = mt * 16 + lr;
      afr[mt] = ld8(Ax + oc * 64 + (((ksh * 4 + q) ^ (lr & 7)) * 8));
    }
    bf16x8 bfr[8];
    #pragma unroll
    for (int rl = 0; rl < 2; ++rl)
      #pragma unroll
      for (int nx = 0; nx < 4; ++nx) {
        int s = rg * 2 + rl + ky;
        bfr[rl * 4 + nx] =
            ld8(smI + ((s * 8 + ksh * 4 + q) * 69 + nx * 16 + lr + kx) * 8);
      }
    #pragma unroll
    for (int mt = 0; mt < 2; ++mt)
      #pragma unroll
      for (int nt = 0; nt < 8; ++nt)
        acc[mt][nt] = mfma16(afr[mt], bfr[nt], acc[mt][nt]);
    if (tap < 24) writeA((tap + 1) & 1);
    __syncthreads();
  }

  // K reduction: ksh=1 waves dump partials, ksh=0 waves add + store
  if (ksh == 1) {
    #pragma unroll
    for (int mt = 0; mt < 2; ++mt)
      #pragma unroll
      for (int rl = 0; rl < 2; ++rl)
        #pragma unroll
        for (int nx = 0; nx < 4; ++nx) {
          int row_l = rg * 2 + rl, px = nx * 16 + lr;
          int oc = mt * 16 + q * 4;
          f32x4 a = acc[mt][rl * 4 + nx];
          #pragma unroll
          for (int r = 0; r < 4; ++r)
            red[(row_l * 64 + px) * 33 + oc + r] = a[r];
        }
  }
  __syncthreads();
  if (ksh == 0) {
    #pragma unroll
    for (int mt = 0; mt < 2; ++mt)
      #pragma unroll
      for (int rl = 0; rl < 2; ++rl)
        #pragma unroll
        for (int nx = 0; nx < 4; ++nx) {
          int row_l = rg * 2 + rl, px = nx * 16 + lr;
          int oc0 = mt * 16 + q * 4;
          f32x4 a = acc[mt][rl * 4 + nx];
          float v[4];
          #pragma unroll
          for (int r = 0; r < 4; ++r)
            v[r] = a[r] + red[(row_l * 64 + px) * 33 + oc0 + r];
          st4(out0 + ((ll)tb * 4096 + (y0 + row_l) * 64 + px) * 32 + oc0,
              v[0], v[1], v[2], v[3]);
        }
  }
}

// ---------------------------------------------------------------------------
// Per-step f1 = leaky(i2f_t + bi + h2f(h) + bh). Block = (b, y): 1 row.
// ALL 25-tap weights preloaded in registers (tap%4 wave split, static index);
// 4-wave K-split + LDS f32 reduce. Grid 512 = 2 blocks/CU co-resident.
__global__ __launch_bounds__(256, 2) void k_h2f4(
    const __bf16* __restrict__ hb, const __bf16* __restrict__ A,
    const float* __restrict__ bi, const float* __restrict__ bh,
    const __bf16* __restrict__ i2f_t, __bf16* __restrict__ f1buf) {
  __shared__ __align__(16) __bf16 smI[5 * 8 * 69 * 8];   // 44160 B
  float* red = (float*)smI;                              // [4][64*33]
  int bi_ = swz_bid();
  int y = bi_ & 63, b = bi_ >> 6;
  int tid = threadIdx.x;
  #pragma unroll
  for (int s = 0; s < 5; ++s) {
    int yr = y - 2 + s;
    stage8<69, 2>(smI + s * (8 * 69 * 8),
                  (yr >= 0 && yr < 64) ? hb + ((ll)(b * 64 + yr) * 64) * 64 : nullptr);
  }
  int wv = __builtin_amdgcn_readfirstlane(tid >> 6);
  int lane = tid & 63, q = lane >> 4, lr = lane & 15;

  bf16x8 apre[7][2][2];
  #pragma unroll
  for (int j = 0; j < 7; ++j) {
    int tap = 4 * j + wv;
    if (tap < 25) {
      #pragma unroll
      for (int ks = 0; ks < 2; ++ks)
        #pragma unroll
        for (int mt = 0; mt < 2; ++mt)
          apre[j][ks][mt] =
              ld8(A + ((ll)(tap * 32 + mt * 16 + lr) * 64 + ks * 32 + q * 8));
    }
  }
  __syncthreads();

  f32x4 zv = {0.f, 0.f, 0.f, 0.f};
  f32x4 acc[2][4];
  #pragma unroll
  for (int mt = 0; mt < 2; ++mt)
    #pragma unroll
    for (int nx = 0; nx < 4; ++nx) acc[mt][nx] = zv;

  #pragma unroll
  for (int j = 0; j < 7; ++j) {
    int tap = 4 * j + wv;
    if (tap < 25) {
      int ky = tap / 5, kx = tap % 5;
      #pragma unroll
      for (int ks = 0; ks < 2; ++ks) {
        bf16x8 bfr[4];
        #pragma unroll
        for (int nx = 0; nx < 4; ++nx)
          bfr[nx] = ld8(smI + ((ky * 8 + ks * 4 + q) * 69 + nx * 16 + lr + kx) * 8);
        #pragma unroll
        for (int mt = 0; mt < 2; ++mt)
          #pragma unroll
          for (int nx = 0; nx < 4; ++nx)
            acc[mt][nx] = mfma16(apre[j][ks][mt], bfr[nx], acc[mt][nx]);
      }
    }
  }
  __syncthreads();   // smI reads done -> safe to overlay red

  #pragma unroll
  for (int mt = 0; mt < 2; ++mt)
    #pragma unroll
    for (int nx = 0; nx < 4; ++nx) {
      int px = nx * 16 + lr, oc = mt * 16 + q * 4;
      f32x4 a = acc[mt][nx];
      #pragma unroll
      for (int r = 0; r < 4; ++r)
        red[wv * 2112 + px * 33 + oc + r] = a[r];
    }
  __syncthreads();

  int px = wv * 16 + (lane >> 2);
  int oc0 = (lane & 3) * 8;
  const __bf16* ip = i2f_t + ((ll)(b * 64 + y) * 64 + px) * 32 + oc0;
  bh8 iv = *(const bh8*)ip;
  bh8 ov;
  #pragma unroll
  for (int j = 0; j < 8; ++j) {
    float v = red[0 * 2112 + px * 33 + oc0 + j] + red[1 * 2112 + px * 33 + oc0 + j] +
              red[2 * 2112 + px * 33 + oc0 + j] + red[3 * 2112 + px * 33 + oc0 + j];
    ov.h[j] = (__bf16)lky(v + (float)iv.h[j] + bi[oc0 + j] + bh[oc0 + j]);
  }
  *(bh8*)(f1buf + ((ll)(b * 64 + y) * 64 + px) * 32 + oc0) = ov;
}

// ---------------------------------------------------------------------------
// Per-step fused: flow conv -> bilinear warp -> ret 1x1 GEMM -> GRU gates.
__global__ __launch_bounds__(256, 3) void k_fwr(
    const __bf16* __restrict__ f1buf, const __bf16* __restrict__ Afl,
    const float* __restrict__ bfl, const __bf16* __restrict__ hb,
    const __bf16* __restrict__ Aret, const float* __restrict__ br,
    const __bf16* __restrict__ i2h_t, const float* __restrict__ hprevf,
    int t0, float* __restrict__ outp, ll osb, __bf16* __restrict__ hbc) {
  __shared__ __align__(16) __bf16 pool[64 * 40 * 8];   // 40960 B
  __shared__ float flows[64 * 17];                     //  4352 B
  __bf16* f1l = pool;
  __bf16* wrp = pool;

  int bi = swz_bid();
  int y = bi & 63, b = bi >> 6;
  int tid = threadIdx.x;
  int wv = __builtin_amdgcn_readfirstlane(tid >> 6);
  int lane = tid & 63, q = lane >> 4, lr = lane & 15;
  int px = wv * 16 + lr;

  #pragma unroll
  for (int r = 0; r < 5; ++r) {
    int yr = y - 2 + r;
    stage4<69, 2>(f1l + r * (4 * 69 * 8),
                  (yr >= 0 && yr < 64) ? f1buf + ((ll)(b * 64 + yr) * 64) * 32 : nullptr);
  }
  __syncthreads();

  f32x4 acc1 = {0.f, 0.f, 0.f, 0.f};
  #pragma unroll
  for (int tap = 0; tap < 25; ++tap) {
    int ky = tap / 5, kx = tap % 5;
    bf16x8 bfr = ld8(f1l + (((ky * 4 + q) * 69) + px + kx) * 8);
    bf16x8 afr = ld8(Afl + ((ll)(tap * 16 + lr) * 32 + q * 8));
    acc1 = mfma16(afr, bfr, acc1);
  }
  __syncthreads();
  #pragma unroll
  for (int r = 0; r < 4; ++r) {
    int oc = q * 4 + r;
    flows[px * 17 + oc] = acc1[r] + (oc < 10 ? bfl[oc] : 0.f);
  }
  __syncthreads();

  {
    int xw = tid & 63, cg = tid >> 6;
    const __bf16* hbb = hb + ((ll)b << 18);
    #pragma unroll
    for (int l = 0; l < 5; ++l) {
      float fx = flows[xw * 17 + 2 * l];
      float fy = flows[xw * 17 + 2 * l + 1];
      float pxf = (float)xw - fx, pyf = (float)y - fy;
      float x0f = floorf(pxf), y0f = floorf(pyf);
      int x0 = (int)x0f, y0 = (int)y0f, x1 = x0 + 1, y1 = y0 + 1;
      float dx = pxf - x0f, dy = pyf - y0f;
      bool vx0 = x0 >= 0 && x0 <= 63, vx1 = x1 >= 0 && x1 <= 63;
      bool vy0 = y0 >= 0 && y0 <= 63, vy1 = y1 >= 0 && y1 <= 63;
      float wA = (vx0 && vy0) ? (1.f - dx) * (1.f - dy) : 0.f;
      float wB = (vx0 && vy1) ? (1.f - dx) * dy : 0.f;
      float wC = (vx1 && vy0) ? dx * (1.f - dy) : 0.f;
      float wD = (vx1 && vy1) ? dx * dy : 0.f;
      int cx0 = min(max(x0, 0), 63), cx1 = min(max(x1, 0), 63);
      int cy0 = min(max(y0, 0), 63), cy1 = min(max(y1, 0), 63);
      int o00 = (cy0 * 64 + cx0) * 64, o10 = (cy1 * 64 + cx0) * 64;
      int o01 = (cy0 * 64 + cx1) * 64, o11 = (cy1 * 64 + cx1) * 64;
      #pragma unroll
      for (int it = 0; it < 2; ++it) {
        int cgp = cg + it * 4;
        int c0 = cgp * 8;
        bf16x8 aA = ld8(hbb + o00 + c0), aB = ld8(hbb + o10 + c0);
        bf16x8 aC = ld8(hbb + o01 + c0), aD = ld8(hbb + o11 + c0);
        bh8 ov;
        #pragma unroll
        for (int i = 0; i < 8; ++i)
          ov.h[i] = (__bf16)(wA * (float)aA[i] + wB * (float)aB[i] +
                             wC * (float)aC[i] + wD * (float)aD[i]);
        int G = l * 8 + cgp;
        int Gs = (G & ~7) | ((G & 7) ^ (xw & 7));
        *(bh8*)(wrp + (xw * 40 + Gs) * 8) = ov;
      }
    }
  }
  __syncthreads();

  f32x4 zv = {0.f, 0.f, 0.f, 0.f};
  f32x4 acc[12];
  #pragma unroll
  for (int mt = 0; mt < 12; ++mt) acc[mt] = zv;
  #pragma unroll
  for (int ks = 0; ks < 10; ++ks) {
    int Gr = ks * 4 + q;
    int Gs = (Gr & ~7) | ((Gr & 7) ^ (px & 7));
    bf16x8 bfr = ld8(wrp + (px * 40 + Gs) * 8);
    #pragma unroll
    for (int mt = 0; mt < 12; ++mt) {
      bf16x8 afr = ld8(Aret + ((ll)(mt * 16 + lr) * 320 + ks * 32 + q * 8));
      acc[mt] = mfma16(afr, bfr, acc[mt]);
    }
  }

  const __bf16* ih = i2h_t + ((ll)(b * 64 + y) * 64 + px) * 192;
  const float* hp = hprevf + (ll)b * osb + y * 64 + px;
  float* ob = outp + (ll)b * osb + y * 64 + px;
  __bf16* hc = hbc + ((ll)(b * 64 + y) * 64 + px) * 64;
  #pragma unroll
  for (int ft = 0; ft < 4; ++ft) {
    int f0 = ft * 16 + q * 4;
    bh4 irv = *(const bh4*)(ih + f0);
    bh4 iuv = *(const bh4*)(ih + f0 + 64);
    bh4 imv = *(const bh4*)(ih + f0 + 128);
    float hn4[4];
    #pragma unroll
    for (int r = 0; r < 4; ++r) {
      int f = f0 + r;
      float hr = acc[ft][r] + br[f];
      float hu = acc[ft + 4][r] + br[f + 64];
      float hm = acc[ft + 8][r] + br[f + 128];
      float rr = 1.f / (1.f + __expf(-((float)irv.h[r] + hr)));
      float uu = 1.f / (1.f + __expf(-((float)iuv.h[r] + hu)));
      float m = lky((float)imv.h[r] + rr * hm);
      float h0 = t0 ? 0.f : hp[(ll)f << 12];
      float hn = uu * h0 + (1.f - uu) * m;
      ob[(ll)f << 12] = hn;
      hn4[r] = hn;
    }
    st4(hc + f0, hn4[0], hn4[1], hn4[2], hn4[3]);
  }
}

// ---------------------------------------------------------------------------
extern "C" void kernel_launch(void* const* d_in, const int* in_sizes, int n_in,
                              void* d_out, int out_size, void* d_ws, size_t ws_size,
                              hipStream_t stream) {
  const float* x      = (const float*)d_in[0];
  const float* W_down = (const float*)d_in[1];
  const float* b_down = (const float*)d_in[2];
  const float* W_i2h  = (const float*)d_in[3];
  const float* b_i2h  = (const float*)d_in[4];
  const float* W_i2f  = (const float*)d_in[5];
  const float* b_i2f  = (const float*)d_in[6];
  const float* W_h2f  = (const float*)d_in[7];
  const float* b_h2f  = (const float*)d_in[8];
  const float* W_flow = (const float*)d_in[9];
  const float* b_flow = (const float*)d_in[10];
  const float* W_ret  = (const float*)d_in[11];
  const float* b_ret  = (const float*)d_in[12];
  float* out = (float*)d_out;

  const ll I2H_T = (ll)NB * 4096 * 192;
  const ll I2F_T = (ll)NB * 4096 * 32;
  const ll H_N   = (ll)NB * 4096 * 64;

  auto align256 = [](ll v) { return (v + 255) & ~255LL; };
  ll fixed = 0;
  fixed += align256(147456LL * 2);
  fixed += align256(110592LL * 2);
  fixed += align256(51200LL * 2);
  fixed += align256(51200LL * 2);
  fixed += align256(12800LL * 2);
  fixed += align256(61440LL * 2);
  fixed += align256((ll)NT * NB * 4096 * 64 * 2);
  fixed += align256((ll)NB * 4096 * 32 * 2);
  fixed += align256(H_N * 2) * 3;
  ll need_full = fixed + align256(NT * I2H_T * 2) + align256(NT * I2F_T * 2);
  int fits = (need_full <= (ll)ws_size);
  int slabT = fits ? NT : 1;

  char* p = (char*)d_ws;
  auto alloc = [&](ll bytes) { char* r = p; p += (bytes + 255) & ~255LL; return r; };
  __bf16* Adown  = (__bf16*)alloc(147456LL * 2);
  __bf16* Ai2h   = (__bf16*)alloc(110592LL * 2);
  __bf16* Afi    = (__bf16*)alloc(51200LL * 2);
  __bf16* Afh    = (__bf16*)alloc(51200LL * 2);
  __bf16* Afl    = (__bf16*)alloc(12800LL * 2);
  __bf16* Aret   = (__bf16*)alloc(61440LL * 2);
  __bf16* seq    = (__bf16*)alloc((ll)NT * NB * 4096 * 64 * 2);
  __bf16* f1buf  = (__bf16*)alloc((ll)NB * 4096 * 32 * 2);
  __bf16* hzb    = (__bf16*)alloc(H_N * 2);
  __bf16* hbufA  = (__bf16*)alloc(H_N * 2);
  __bf16* hbufB  = (__bf16*)alloc(H_N * 2);
  __bf16* i2h_sl = (__bf16*)alloc(slabT * I2H_T * 2);
  __bf16* i2f_sl = (__bf16*)alloc(slabT * I2F_T * 2);
  if (p > (char*)d_ws + ws_size) return;

  hipMemsetAsync(hzb, 0, (size_t)H_N * 2, stream);

  k_prep<<<1698, 256, 0, stream>>>(W_down, W_i2h, W_i2f, W_h2f, W_flow, W_ret,
                                   Adown, Ai2h, Afi, Afh, Afl, Aret);
  k_down<<<NB * 64 * 4, 256, 0, stream>>>(x, Adown, b_down, seq);

  if (fits) {
    k_i2h4<<<NT * NB * 2 * 16, 256, 0, stream>>>(seq, Ai2h, b_i2h, i2h_sl);
    k_i2fb<<<NT * NB * 16, 256, 0, stream>>>(seq, Afi, i2f_sl);
  }

  const ll osb = (ll)NT * NF * HWSZ;
  for (int t = 0; t < NT; ++t) {
    const __bf16* xt0 = seq + (ll)t * NB * 4096 * 64;
    if (!fits) {
      k_i2h4<<<NB * 2 * 16, 256, 0, stream>>>(xt0, Ai2h, b_i2h, i2h_sl);
      k_i2fb<<<NB * 16, 256, 0, stream>>>(xt0, Afi, i2f_sl);
    }
    int ti = fits ? t : 0;
    const __bf16* hb = (t == 0) ? hzb : ((t & 1) ? hbufA : hbufB);
    __bf16* hbc = (t & 1) ? hbufB : hbufA;
    const float* hpf = (t == 0) ? out : out + (ll)(t - 1) * NF * HWSZ;

    k_h2f4<<<NB * 64, 256, 0, stream>>>(hb, Afh, b_i2f, b_h2f,
                                        i2f_sl + (ll)ti * I2F_T, f1buf);
    k_fwr<<<NB * 64, 256, 0, stream>>>(f1buf, Afl, b_flow, hb, Aret, b_ret,
                                       i2h_sl + (ll)ti * I2H_T, hpf,
                                       (t == 0) ? 1 : 0,
                                       out + (ll)t * NF * HWSZ, osb, hbc);
  }
}

// Round 7
// 884.506 us; speedup vs baseline: 1.5491x; 1.1066x over previous
//
#include <hip/hip_runtime.h>
#include <cstdint>

typedef long long ll;
typedef __bf16 bf16x8 __attribute__((ext_vector_type(8)));
typedef float f32x4 __attribute__((ext_vector_type(4)));
typedef unsigned int u32x4 __attribute__((ext_vector_type(4)));

#define NB 8
#define NT 12
#define NF 64
#define HWSZ 4096

struct alignas(8)  bh4 { __bf16 h[4]; };
struct alignas(16) bh8 { __bf16 h[8]; };

static __device__ inline f32x4 mfma16(bf16x8 a, bf16x8 b, f32x4 c) {
  return __builtin_amdgcn_mfma_f32_16x16x32_bf16(a, b, c, 0, 0, 0);
}
static __device__ inline bf16x8 ld8(const __bf16* p) {
  u32x4 u = *(const u32x4*)p;
  return __builtin_bit_cast(bf16x8, u);
}
static __device__ inline void st4(__bf16* p, float a0, float a1, float a2, float a3) {
  bh4 t; t.h[0] = (__bf16)a0; t.h[1] = (__bf16)a1; t.h[2] = (__bf16)a2; t.h[3] = (__bf16)a3;
  *(bh4*)p = t;
}
static __device__ inline float lky(float a) { return a >= 0.f ? a : 0.2f * a; }

// XCD-chunked swizzle (grid divisible by 8): neighbors share an XCD L2.
static __device__ inline int swz_bid() {
  int bid = blockIdx.x;
  return ((gridDim.x & 7) == 0) ? (bid & 7) * (gridDim.x >> 3) + (bid >> 3) : bid;
}

// Stage one row of a 64-ch NHWC bf16 map into LDS [g8][W][8] (full channels).
template<int W, int HALO>
static __device__ void stage8(__bf16* dst, const __bf16* grow) {
  int tid = threadIdx.x;
  u32x4 zz = {0u, 0u, 0u, 0u};
  #pragma unroll
  for (int it = 0; it < 2; ++it) {
    int i = tid + it * 256;
    int xr = i >> 3, g = i & 7, xi = xr + HALO;
    u32x4 v = zz;
    if (grow) v = *(const u32x4*)(grow + xr * 64 + g * 8);
    *(u32x4*)(dst + (g * W + xi) * 8) = v;
  }
  if (tid < 16 * HALO) {
    int h = tid >> 3, g = tid & 7;
    int xi = (h < HALO) ? h : 64 + h;
    *(u32x4*)(dst + (g * W + xi) * 8) = zz;
  }
}

// ---------------------------------------------------------------------------
// Weight pre-transform: bf16 fragment-friendly layouts.
__global__ __launch_bounds__(256) void k_prep(
    const float* __restrict__ Wd, const float* __restrict__ Wc,
    const float* __restrict__ Wi, const float* __restrict__ Wh,
    const float* __restrict__ Wfl, const float* __restrict__ Wret,
    __bf16* __restrict__ Adown, __bf16* __restrict__ Ai2h,
    __bf16* __restrict__ Afi, __bf16* __restrict__ Afh,
    __bf16* __restrict__ Afl, __bf16* __restrict__ Aret) {
  int n = blockIdx.x * 256 + threadIdx.x;
  if (n < 147456) {                            // Adown[oc][k]
    Adown[n] = (__bf16)Wd[n];
  } else if (n < 258048) {                     // Ai2h[tap][o192][c64]
    int i = n - 147456;
    int tap = i / 12288, o = (i % 12288) / 64, c = i % 64;
    Ai2h[i] = (__bf16)Wc[(o * 64 + c) * 9 + tap];
  } else if (n < 309248) {                     // Afi[tap][o32][c64]
    int i = n - 258048;
    int tap = i / 2048, o = (i % 2048) / 64, c = i % 64;
    Afi[i] = (__bf16)Wi[(o * 64 + c) * 25 + tap];
  } else if (n < 360448) {                     // Afh[tap][o32][c64]
    int i = n - 309248;
    int tap = i / 2048, o = (i % 2048) / 64, c = i % 64;
    Afh[i] = (__bf16)Wh[(o * 64 + c) * 25 + tap];
  } else if (n < 373248) {                     // Afl[tap][o16 pad][c32]
    int i = n - 360448;
    int tap = i / 512, o = (i % 512) / 32, c = i % 32;
    Afl[i] = (__bf16)(o < 10 ? Wfl[(o * 32 + c) * 25 + tap] : 0.f);
  } else if (n < 434688) {                     // Aret[o192][c320]
    Aret[n - 373248] = (__bf16)Wret[n - 373248];
  }
}

// ---------------------------------------------------------------------------
// Downsample conv as MFMA implicit GEMM. (b,y,zQ); zQ splits M=768 into 4.
__global__ __launch_bounds__(256) void k_down(
    const float* __restrict__ x, const __bf16* __restrict__ Adown,
    const float* __restrict__ bd, __bf16* __restrict__ seq) {
  __shared__ __bf16 smd[6240];
  int bi = swz_bid();
  int zQ = bi & 3, y = (bi >> 2) & 63, b = bi >> 8;
  int tid = threadIdx.x;
  for (int i = tid; i < 6240; i += 256) {
    int ic = i / 520, rem = i % 520, ky = rem / 130, xi = rem % 130;
    int ix = xi - 1, iy = 2 * y - 1 + ky;
    float v = (ix >= 0 && ix < 128 && iy >= 0 && iy < 128)
                  ? x[(((ll)(b * 12 + ic) * 128 + iy) << 7) + ix] : 0.f;
    smd[i] = (__bf16)v;
  }
  __syncthreads();
  int wv = __builtin_amdgcn_readfirstlane(tid >> 6);
  int lane = tid & 63, q = lane >> 4, lr = lane & 15;
  int px = wv * 16 + lr;
  f32x4 zv = {0.f, 0.f, 0.f, 0.f};
  f32x4 acc[12];
  #pragma unroll
  for (int mt = 0; mt < 12; ++mt) acc[mt] = zv;

  for (int ks = 0; ks < 6; ++ks) {
    int k0 = ks * 32 + q * 8;
    int ic = k0 >> 4, ky0 = (k0 >> 2) & 3;
    const __bf16* rp = smd + (ic * 4 + ky0) * 130 + 2 * px;
    bh8 bb;
    #pragma unroll
    for (int j = 0; j < 8; ++j)
      bb.h[j] = rp[(j >> 2) * 130 + (j & 3)];
    bf16x8 bfr = __builtin_bit_cast(bf16x8, bb);
    #pragma unroll
    for (int mt = 0; mt < 12; ++mt) {
      bf16x8 afr = ld8(Adown + ((ll)(zQ * 192 + mt * 16 + lr) * 192 + k0));
      acc[mt] = mfma16(afr, bfr, acc[mt]);
    }
  }
  #pragma unroll
  for (int mt = 0; mt < 12; ++mt) {
    int t_idx = zQ * 3 + (mt >> 2);
    int f0 = (mt & 3) * 16 + q * 4;
    float v[4];
    #pragma unroll
    for (int r = 0; r < 4; ++r)
      v[r] = lky(acc[mt][r] + bd[zQ * 192 + mt * 16 + q * 4 + r]);
    st4(seq + (((ll)(t_idx * NB + b) * 4096 + y * 64 + px) * 64 + f0),
        v[0], v[1], v[2], v[3]);
  }
}

// ---------------------------------------------------------------------------
// i2h 3x3 conv, A staged per-tap in double-buffered LDS (no global loads in
// the MFMA loop). Block = (tb, och, yg): 96 oc x 4 rows x 64 px.
__global__ __launch_bounds__(256, 2) void k_i2h4(
    const __bf16* __restrict__ in0, const __bf16* __restrict__ A,
    const float* __restrict__ bc, __bf16* __restrict__ out0) {
  __shared__ __align__(16) __bf16 smI[6 * 8 * 67 * 8];   // 51456 B
  __shared__ __align__(16) __bf16 smA[2][96 * 64];       // 24576 B
  int bi_ = swz_bid();
  int yg = bi_ & 15, och = (bi_ >> 4) & 1, tb = bi_ >> 5;
  int y0 = yg * 4;
  const __bf16* base = in0 + (ll)tb * (4096 * 64);
  const __bf16* Ab = A + ((ll)och * 96) * 64;
  int tid = threadIdx.x;
  #pragma unroll
  for (int s = 0; s < 6; ++s) {
    int yr = y0 - 1 + s;
    stage8<67, 1>(smI + s * (8 * 67 * 8),
                  (yr >= 0 && yr < 64) ? base + (ll)yr * 64 * 64 : nullptr);
  }
  u32x4 ar[3];
  auto loadA = [&](int tap) {
    #pragma unroll
    for (int it = 0; it < 3; ++it) {
      int j = it * 256 + tid;
      ar[it] = *(const u32x4*)(Ab + (ll)tap * (192 * 64) + j * 8);
    }
  };
  auto writeA = [&](int buf) {
    #pragma unroll
    for (int it = 0; it < 3; ++it) {
      int j = it * 256 + tid;
      int oc = j >> 3, g = j & 7;
      *(u32x4*)(smA[buf] + oc * 64 + ((g ^ (oc & 7)) * 8)) = ar[it];
    }
  };
  loadA(0);
  writeA(0);
  __syncthreads();

  int wv = __builtin_amdgcn_readfirstlane(tid >> 6);
  int lane = tid & 63, q = lane >> 4, lr = lane & 15;
  int mh = wv & 1, rg = wv >> 1;
  f32x4 zv = {0.f, 0.f, 0.f, 0.f};
  f32x4 acc[3][8];
  #pragma unroll
  for (int mt = 0; mt < 3; ++mt)
    #pragma unroll
    for (int nt = 0; nt < 8; ++nt) acc[mt][nt] = zv;

  for (int tap = 0; tap < 9; ++tap) {
    if (tap < 8) loadA(tap + 1);            // issue early (T14)
    int ky = tap / 3, kx = tap % 3;
    const __bf16* Ax = smA[tap & 1];
    #pragma unroll
    for (int ks = 0; ks < 2; ++ks) {
      bf16x8 afr[3];
      #pragma unroll
      for (int mt = 0; mt < 3; ++mt) {
        int oc = mh * 48 + mt * 16 + lr;
        afr[mt] = ld8(Ax + oc * 64 + (((ks * 4 + q) ^ (lr & 7)) * 8));
      }
      bf16x8 bfr[8];
      #pragma unroll
      for (int rl = 0; rl < 2; ++rl)
        #pragma unroll
        for (int nx = 0; nx < 4; ++nx) {
          int s = rg * 2 + rl + ky;
          bfr[rl * 4 + nx] =
              ld8(smI + ((s * 8 + ks * 4 + q) * 67 + nx * 16 + lr + kx) * 8);
        }
      #pragma unroll
      for (int mt = 0; mt < 3; ++mt)
        #pragma unroll
        for (int nt = 0; nt < 8; ++nt)
          acc[mt][nt] = mfma16(afr[mt], bfr[nt], acc[mt][nt]);
    }
    if (tap < 8) writeA((tap + 1) & 1);     // write late
    __syncthreads();
  }

  #pragma unroll
  for (int rl = 0; rl < 2; ++rl)
    #pragma unroll
    for (int nx = 0; nx < 4; ++nx) {
      int row = y0 + rg * 2 + rl, px = nx * 16 + lr;
      __bf16* op = out0 + ((ll)tb * 4096 + row * 64 + px) * 192;
      #pragma unroll
      for (int mt = 0; mt < 3; ++mt) {
        int oc0 = och * 96 + mh * 48 + mt * 16 + q * 4;
        f32x4 a = acc[mt][rl * 4 + nx];
        st4(op + oc0, a[0] + bc[oc0], a[1] + bc[oc0 + 1],
                      a[2] + bc[oc0 + 2], a[3] + bc[oc0 + 3]);
      }
    }
}

// ---------------------------------------------------------------------------
// Batched i2f 5x5 (no bias). A per-tap in double-buffered LDS; K split across
// wave pairs (ksh) with f32 LDS reduction (reuses input region).
__global__ __launch_bounds__(256, 2) void k_i2fb(
    const __bf16* __restrict__ in0, const __bf16* __restrict__ A,
    __bf16* __restrict__ out0) {
  __shared__ __align__(16) __bf16 smI[8 * 8 * 69 * 8];   // 70656 B
  __shared__ __align__(16) __bf16 smA[2][32 * 64];       // 8192 B
  float* red = (float*)smI;                              // [4][64][33] later
  int bi_ = swz_bid();
  int yg = bi_ & 15, tb = bi_ >> 4;
  int y0 = yg * 4;
  const __bf16* base = in0 + (ll)tb * (4096 * 64);
  int tid = threadIdx.x;
  #pragma unroll
  for (int s = 0; s < 8; ++s) {
    int yr = y0 - 2 + s;
    stage8<69, 2>(smI + s * (8 * 69 * 8),
                  (yr >= 0 && yr < 64) ? base + (ll)yr * 64 * 64 : nullptr);
  }
  u32x4 ar;
  auto loadA = [&](int tap) { ar = *(const u32x4*)(A + (ll)tap * 2048 + tid * 8); };
  auto writeA = [&](int buf) {
    int oc = tid >> 3, g = tid & 7;
    *(u32x4*)(smA[buf] + oc * 64 + ((g ^ (oc & 7)) * 8)) = ar;
  };
  loadA(0);
  writeA(0);
  __syncthreads();

  int wv = __builtin_amdgcn_readfirstlane(tid >> 6);
  int lane = tid & 63, q = lane >> 4, lr = lane & 15;
  int rg = wv & 1, ksh = wv >> 1;
  f32x4 zv = {0.f, 0.f, 0.f, 0.f};
  f32x4 acc[2][8];
  #pragma unroll
  for (int mt = 0; mt < 2; ++mt)
    #pragma unroll
    for (int nt = 0; nt < 8; ++nt) acc[mt][nt] = zv;

  for (int tap = 0; tap < 25; ++tap) {
    if (tap < 24) loadA(tap + 1);
    int ky = tap / 5, kx = tap % 5;
    const __bf16* Ax = smA[tap & 1];
    bf16x8 afr[2];
    #pragma unroll
    for (int mt = 0; mt < 2; ++mt) {
      int oc = mt * 16 + lr;
      afr[mt] = ld8(Ax + oc * 64 + (((ksh * 4 + q) ^ (lr & 7)) * 8));
    }
    bf16x8 bfr[8];
    #pragma unroll
    for (int rl = 0; rl < 2; ++rl)
      #pragma unroll
      for (int nx = 0; nx < 4; ++nx) {
        int s = rg * 2 + rl + ky;
        bfr[rl * 4 + nx] =
            ld8(smI + ((s * 8 + ksh * 4 + q) * 69 + nx * 16 + lr + kx) * 8);
      }
    #pragma unroll
    for (int mt = 0; mt < 2; ++mt)
      #pragma unroll
      for (int nt = 0; nt < 8; ++nt)
        acc[mt][nt] = mfma16(afr[mt], bfr[nt], acc[mt][nt]);
    if (tap < 24) writeA((tap + 1) & 1);
    __syncthreads();
  }

  if (ksh == 1) {
    #pragma unroll
    for (int mt = 0; mt < 2; ++mt)
      #pragma unroll
      for (int rl = 0; rl < 2; ++rl)
        #pragma unroll
        for (int nx = 0; nx < 4; ++nx) {
          int row_l = rg * 2 + rl, px = nx * 16 + lr;
          int oc = mt * 16 + q * 4;
          f32x4 a = acc[mt][rl * 4 + nx];
          #pragma unroll
          for (int r = 0; r < 4; ++r)
            red[(row_l * 64 + px) * 33 + oc + r] = a[r];
        }
  }
  __syncthreads();
  if (ksh == 0) {
    #pragma unroll
    for (int mt = 0; mt < 2; ++mt)
      #pragma unroll
      for (int rl = 0; rl < 2; ++rl)
        #pragma unroll
        for (int nx = 0; nx < 4; ++nx) {
          int row_l = rg * 2 + rl, px = nx * 16 + lr;
          int oc0 = mt * 16 + q * 4;
          f32x4 a = acc[mt][rl * 4 + nx];
          float v[4];
          #pragma unroll
          for (int r = 0; r < 4; ++r)
            v[r] = a[r] + red[(row_l * 64 + px) * 33 + oc0 + r];
          st4(out0 + ((ll)tb * 4096 + (y0 + row_l) * 64 + px) * 32 + oc0,
              v[0], v[1], v[2], v[3]);
        }
  }
}

// ---------------------------------------------------------------------------
// Per-step f1 = leaky(i2f_t + bi + h2f(h) + bh). Block = (b, y, xh): 1 row x
// 32 px. Tap-split 4 waves, 2-deep A-frag ring (8 frags), LDS 23.7 KB,
// (256,4) -> 4 blocks/CU. Grid 1024.
__global__ __launch_bounds__(256, 4) void k_h2f5(
    const __bf16* __restrict__ hb, const __bf16* __restrict__ A,
    const float* __restrict__ bi, const float* __restrict__ bh,
    const __bf16* __restrict__ i2f_t, __bf16* __restrict__ f1buf) {
  __shared__ __align__(16) __bf16 smI[5 * 8 * 37 * 8];   // 23680 B
  float* red = (float*)smI;                              // [4][32*33] overlay
  int bi_ = swz_bid();
  int xh = bi_ & 1, y = (bi_ >> 1) & 63, b = bi_ >> 7;
  int x0 = xh * 32;
  int tid = threadIdx.x;
  u32x4 zz = {0u, 0u, 0u, 0u};
  for (int i = tid; i < 5 * 296; i += 256) {
    int s = i / 296, rem = i % 296, xi = rem >> 3, g = rem & 7;
    int yr = y - 2 + s, xg = x0 - 2 + xi;
    u32x4 v = zz;
    if (yr >= 0 && yr < 64 && xg >= 0 && xg < 64)
      v = *(const u32x4*)(hb + ((ll)(b * 64 + yr) * 64 + xg) * 64 + g * 8);
    *(u32x4*)(smI + ((s * 8 + g) * 37 + xi) * 8) = v;
  }
  int wv = __builtin_amdgcn_readfirstlane(tid >> 6);
  int lane = tid & 63, q = lane >> 4, lr = lane & 15;

  bf16x8 cur[2][2], nxt[2][2];
  auto loadAt = [&](int tap, bf16x8 a[2][2]) {
    #pragma unroll
    for (int ks = 0; ks < 2; ++ks)
      #pragma unroll
      for (int mt = 0; mt < 2; ++mt)
        a[ks][mt] = ld8(A + ((ll)(tap * 32 + mt * 16 + lr) * 64 + ks * 32 + q * 8));
  };
  loadAt(wv, cur);            // first tap for this wave (wv < 25 always)
  __syncthreads();

  f32x4 zv = {0.f, 0.f, 0.f, 0.f};
  f32x4 acc[2][2];
  #pragma unroll
  for (int mt = 0; mt < 2; ++mt)
    #pragma unroll
    for (int nx = 0; nx < 2; ++nx) acc[mt][nx] = zv;

  #pragma unroll
  for (int j = 0; j < 7; ++j) {
    int tap = 4 * j + wv;
    if (tap < 25) {
      if (tap + 4 < 25) loadAt(tap + 4, nxt);
      int ky = tap / 5, kx = tap % 5;
      #pragma unroll
      for (int ks = 0; ks < 2; ++ks) {
        bf16x8 bfr[2];
        #pragma unroll
        for (int nx = 0; nx < 2; ++nx)
          bfr[nx] = ld8(smI + ((ky * 8 + ks * 4 + q) * 37 + nx * 16 + lr + kx) * 8);
        #pragma unroll
        for (int mt = 0; mt < 2; ++mt)
          #pragma unroll
          for (int nx = 0; nx < 2; ++nx)
            acc[mt][nx] = mfma16(cur[ks][mt], bfr[nx], acc[mt][nx]);
      }
      #pragma unroll
      for (int ks = 0; ks < 2; ++ks)
        #pragma unroll
        for (int mt = 0; mt < 2; ++mt) cur[ks][mt] = nxt[ks][mt];
    }
  }
  __syncthreads();   // smI reads done -> red overlay safe

  #pragma unroll
  for (int mt = 0; mt < 2; ++mt)
    #pragma unroll
    for (int nx = 0; nx < 2; ++nx) {
      int pxl = nx * 16 + lr, oc = mt * 16 + q * 4;
      f32x4 a = acc[mt][nx];
      #pragma unroll
      for (int r = 0; r < 4; ++r)
        red[wv * 1056 + pxl * 33 + oc + r] = a[r];
    }
  __syncthreads();

  int pxl = tid >> 3, oc0 = (tid & 7) * 4;
  const __bf16* ip = i2f_t + ((ll)(b * 64 + y) * 64 + x0 + pxl) * 32 + oc0;
  bh4 iv = *(const bh4*)ip;
  float v[4];
  #pragma unroll
  for (int r = 0; r < 4; ++r) {
    float s = red[0 * 1056 + pxl * 33 + oc0 + r] + red[1 * 1056 + pxl * 33 + oc0 + r] +
              red[2 * 1056 + pxl * 33 + oc0 + r] + red[3 * 1056 + pxl * 33 + oc0 + r];
    v[r] = lky(s + (float)iv.h[r] + bi[oc0 + r] + bh[oc0 + r]);
  }
  st4(f1buf + ((ll)(b * 64 + y) * 64 + x0 + pxl) * 32 + oc0, v[0], v[1], v[2], v[3]);
}

// ---------------------------------------------------------------------------
// Per-step fused: flow conv -> warp -> ret 1x1 GEMM (M-split across waves) ->
// LDS f32 exchange -> GRU gates. Block = (b, y, xh): 1 row x 32 px. Grid 1024.
// LDS union 27.5 KB, (256,4) -> 4 blocks/CU.
__global__ __launch_bounds__(256, 4) void k_fwr2(
    const __bf16* __restrict__ f1buf, const __bf16* __restrict__ Afl,
    const float* __restrict__ bfl, const __bf16* __restrict__ hb,
    const __bf16* __restrict__ Aret, const float* __restrict__ br,
    const __bf16* __restrict__ i2h_t, const float* __restrict__ hprevf,
    int t0, float* __restrict__ outp, ll osb, __bf16* __restrict__ hbc) {
  __shared__ __align__(16) float exbuf[192 * 33];   // 25344 B (union region)
  __shared__ float flows[32 * 17];                  //  2176 B
  __bf16* f1l = (__bf16*)exbuf;                     // [5][4][37][8] = 11840 B
  __bf16* wrp = (__bf16*)exbuf;                     // [32][40][8]   = 20480 B

  int bi = swz_bid();
  int xh = bi & 1, y = (bi >> 1) & 63, b = bi >> 7;
  int x0 = xh * 32;
  int tid = threadIdx.x;
  int wv = __builtin_amdgcn_readfirstlane(tid >> 6);
  int lane = tid & 63, q = lane >> 4, lr = lane & 15;

  // phase 1: stage f1 rows y-2..y+2, x window x0-2..x0+34
  u32x4 zz = {0u, 0u, 0u, 0u};
  for (int i = tid; i < 5 * 148; i += 256) {
    int s = i / 148, rem = i % 148, xi = rem >> 2, g = rem & 3;
    int yr = y - 2 + s, xg = x0 - 2 + xi;
    u32x4 v = zz;
    if (yr >= 0 && yr < 64 && xg >= 0 && xg < 64)
      v = *(const u32x4*)(f1buf + ((ll)(b * 64 + yr) * 64 + xg) * 32 + g * 8);
    *(u32x4*)(f1l + ((s * 4 + g) * 37 + xi) * 8) = v;
  }
  __syncthreads();

  // phase 2: flow conv (waves 0-1, nt = wv), M=16 (10 used), K=25x32
  if (wv < 2) {
    f32x4 acc1 = {0.f, 0.f, 0.f, 0.f};
    #pragma unroll
    for (int tap = 0; tap < 25; ++tap) {
      int ky = tap / 5, kx = tap % 5;
      bf16x8 bfr = ld8(f1l + ((ky * 4 + q) * 37 + wv * 16 + lr + kx) * 8);
      bf16x8 afr = ld8(Afl + ((ll)(tap * 16 + lr) * 32 + q * 8));
      acc1 = mfma16(afr, bfr, acc1);
    }
    #pragma unroll
    for (int r = 0; r < 4; ++r) {
      int oc = q * 4 + r;
      flows[(wv * 16 + lr) * 17 + oc] = acc1[r] + (oc < 10 ? bfl[oc] : 0.f);
    }
  }
  __syncthreads();   // flows visible; f1l reads done -> wrp overlay safe

  // phase 3: warp 5 trajectories into wrp [pxl][G40][8], G-low3 XOR pxl-swizzle
  {
    int pxl = tid & 31, cg = tid >> 5;       // cg 0..7
    int xw = x0 + pxl;
    const __bf16* hbb = hb + ((ll)b << 18);
    #pragma unroll
    for (int l = 0; l < 5; ++l) {
      float fx = flows[pxl * 17 + 2 * l];
      float fy = flows[pxl * 17 + 2 * l + 1];
      float pxf = (float)xw - fx, pyf = (float)y - fy;
      float x0f = floorf(pxf), y0f = floorf(pyf);
      int xx0 = (int)x0f, yy0 = (int)y0f, xx1 = xx0 + 1, yy1 = yy0 + 1;
      float dx = pxf - x0f, dy = pyf - y0f;
      bool vx0 = xx0 >= 0 && xx0 <= 63, vx1 = xx1 >= 0 && xx1 <= 63;
      bool vy0 = yy0 >= 0 && yy0 <= 63, vy1 = yy1 >= 0 && yy1 <= 63;
      float wA = (vx0 && vy0) ? (1.f - dx) * (1.f - dy) : 0.f;
      float wB = (vx0 && vy1) ? (1.f - dx) * dy : 0.f;
      float wC = (vx1 && vy0) ? dx * (1.f - dy) : 0.f;
      float wD = (vx1 && vy1) ? dx * dy : 0.f;
      int cx0 = min(max(xx0, 0), 63), cx1 = min(max(xx1, 0), 63);
      int cy0 = min(max(yy0, 0), 63), cy1 = min(max(yy1, 0), 63);
      int o00 = (cy0 * 64 + cx0) * 64, o10 = (cy1 * 64 + cx0) * 64;
      int o01 = (cy0 * 64 + cx1) * 64, o11 = (cy1 * 64 + cx1) * 64;
      int c0 = cg * 8;
      bf16x8 aA = ld8(hbb + o00 + c0), aB = ld8(hbb + o10 + c0);
      bf16x8 aC = ld8(hbb + o01 + c0), aD = ld8(hbb + o11 + c0);
      bh8 ov;
      #pragma unroll
      for (int i = 0; i < 8; ++i)
        ov.h[i] = (__bf16)(wA * (float)aA[i] + wB * (float)aB[i] +
                           wC * (float)aC[i] + wD * (float)aD[i]);
      int G = l * 8 + cg;
      int Gs = (G & ~7) | ((G & 7) ^ (pxl & 7));
      *(bh8*)(wrp + (pxl * 40 + Gs) * 8) = ov;
    }
  }
  __syncthreads();

  // phase 4: ret 1x1 GEMM, M-split: wave w owns oc rows (w*3+mt)*16, all 32 px
  f32x4 zv = {0.f, 0.f, 0.f, 0.f};
  f32x4 acc[3][2];
  #pragma unroll
  for (int mt = 0; mt < 3; ++mt)
    #pragma unroll
    for (int nt = 0; nt < 2; ++nt) acc[mt][nt] = zv;
  #pragma unroll
  for (int ks = 0; ks < 10; ++ks) {
    bf16x8 bfr[2];
    #pragma unroll
    for (int nt = 0; nt < 2; ++nt) {
      int pxl = nt * 16 + lr;
      int Gr = ks * 4 + q;
      int Gs = (Gr & ~7) | ((Gr & 7) ^ (pxl & 7));
      bfr[nt] = ld8(wrp + (pxl * 40 + Gs) * 8);
    }
    #pragma unroll
    for (int mt = 0; mt < 3; ++mt) {
      bf16x8 afr = ld8(Aret + ((ll)((wv * 3 + mt) * 16 + lr) * 320 + ks * 32 + q * 8));
      #pragma unroll
      for (int nt = 0; nt < 2; ++nt)
        acc[mt][nt] = mfma16(afr, bfr[nt], acc[mt][nt]);
    }
  }
  __syncthreads();   // wrp dead -> exbuf overlay safe

  // phase 5: f32 exchange [192 oc][33 pad] x 32 px
  #pragma unroll
  for (int mt = 0; mt < 3; ++mt)
    #pragma unroll
    for (int nt = 0; nt < 2; ++nt) {
      int oc = (wv * 3 + mt) * 16 + q * 4;
      int pxl = nt * 16 + lr;
      #pragma unroll
      for (int r = 0; r < 4; ++r)
        exbuf[(oc + r) * 33 + pxl] = acc[mt][nt][r];
    }
  __syncthreads();

  // phase 6: gates — thread: pxl = tid>>3 (0..31), f0 = (tid&7)*8
  int pxl = tid >> 3, f0 = (tid & 7) * 8;
  int xg = x0 + pxl;
  const __bf16* ih = i2h_t + ((ll)(b * 64 + y) * 64 + xg) * 192;
  const float* hp = hprevf + (ll)b * osb + y * 64 + xg;
  float* ob = outp + (ll)b * osb + y * 64 + xg;
  __bf16* hc = hbc + ((ll)(b * 64 + y) * 64 + xg) * 64 + f0;
  bh8 irv = *(const bh8*)(ih + f0);
  bh8 iuv = *(const bh8*)(ih + 64 + f0);
  bh8 imv = *(const bh8*)(ih + 128 + f0);
  bh8 hv;
  #pragma unroll
  for (int j = 0; j < 8; ++j) {
    int f = f0 + j;
    float hr = exbuf[f * 33 + pxl] + br[f];
    float hu = exbuf[(f + 64) * 33 + pxl] + br[f + 64];
    float hm = exbuf[(f + 128) * 33 + pxl] + br[f + 128];
    float rr = 1.f / (1.f + __expf(-((float)irv.h[j] + hr)));
    float uu = 1.f / (1.f + __expf(-((float)iuv.h[j] + hu)));
    float m = lky((float)imv.h[j] + rr * hm);
    float h0 = t0 ? 0.f : hp[(ll)f << 12];
    float hn = uu * h0 + (1.f - uu) * m;
    ob[(ll)f << 12] = hn;
    hv.h[j] = (__bf16)hn;
  }
  *(bh8*)hc = hv;
}

// ---------------------------------------------------------------------------
extern "C" void kernel_launch(void* const* d_in, const int* in_sizes, int n_in,
                              void* d_out, int out_size, void* d_ws, size_t ws_size,
                              hipStream_t stream) {
  const float* x      = (const float*)d_in[0];
  const float* W_down = (const float*)d_in[1];
  const float* b_down = (const float*)d_in[2];
  const float* W_i2h  = (const float*)d_in[3];
  const float* b_i2h  = (const float*)d_in[4];
  const float* W_i2f  = (const float*)d_in[5];
  const float* b_i2f  = (const float*)d_in[6];
  const float* W_h2f  = (const float*)d_in[7];
  const float* b_h2f  = (const float*)d_in[8];
  const float* W_flow = (const float*)d_in[9];
  const float* b_flow = (const float*)d_in[10];
  const float* W_ret  = (const float*)d_in[11];
  const float* b_ret  = (const float*)d_in[12];
  float* out = (float*)d_out;

  const ll I2H_T = (ll)NB * 4096 * 192;
  const ll I2F_T = (ll)NB * 4096 * 32;
  const ll H_N   = (ll)NB * 4096 * 64;

  auto align256 = [](ll v) { return (v + 255) & ~255LL; };
  ll fixed = 0;
  fixed += align256(147456LL * 2);
  fixed += align256(110592LL * 2);
  fixed += align256(51200LL * 2);
  fixed += align256(51200LL * 2);
  fixed += align256(12800LL * 2);
  fixed += align256(61440LL * 2);
  fixed += align256((ll)NT * NB * 4096 * 64 * 2);
  fixed += align256((ll)NB * 4096 * 32 * 2);
  fixed += align256(H_N * 2) * 3;
  ll need_full = fixed + align256(NT * I2H_T * 2) + align256(NT * I2F_T * 2);
  int fits = (need_full <= (ll)ws_size);
  int slabT = fits ? NT : 1;

  char* p = (char*)d_ws;
  auto alloc = [&](ll bytes) { char* r = p; p += (bytes + 255) & ~255LL; return r; };
  __bf16* Adown  = (__bf16*)alloc(147456LL * 2);
  __bf16* Ai2h   = (__bf16*)alloc(110592LL * 2);
  __bf16* Afi    = (__bf16*)alloc(51200LL * 2);
  __bf16* Afh    = (__bf16*)alloc(51200LL * 2);
  __bf16* Afl    = (__bf16*)alloc(12800LL * 2);
  __bf16* Aret   = (__bf16*)alloc(61440LL * 2);
  __bf16* seq    = (__bf16*)alloc((ll)NT * NB * 4096 * 64 * 2);
  __bf16* f1buf  = (__bf16*)alloc((ll)NB * 4096 * 32 * 2);
  __bf16* hzb    = (__bf16*)alloc(H_N * 2);
  __bf16* hbufA  = (__bf16*)alloc(H_N * 2);
  __bf16* hbufB  = (__bf16*)alloc(H_N * 2);
  __bf16* i2h_sl = (__bf16*)alloc(slabT * I2H_T * 2);
  __bf16* i2f_sl = (__bf16*)alloc(slabT * I2F_T * 2);
  if (p > (char*)d_ws + ws_size) return;

  hipMemsetAsync(hzb, 0, (size_t)H_N * 2, stream);

  k_prep<<<1698, 256, 0, stream>>>(W_down, W_i2h, W_i2f, W_h2f, W_flow, W_ret,
                                   Adown, Ai2h, Afi, Afh, Afl, Aret);
  k_down<<<NB * 64 * 4, 256, 0, stream>>>(x, Adown, b_down, seq);

  if (fits) {
    k_i2h4<<<NT * NB * 2 * 16, 256, 0, stream>>>(seq, Ai2h, b_i2h, i2h_sl);
    k_i2fb<<<NT * NB * 16, 256, 0, stream>>>(seq, Afi, i2f_sl);
  }

  const ll osb = (ll)NT * NF * HWSZ;
  for (int t = 0; t < NT; ++t) {
    const __bf16* xt0 = seq + (ll)t * NB * 4096 * 64;
    if (!fits) {
      k_i2h4<<<NB * 2 * 16, 256, 0, stream>>>(xt0, Ai2h, b_i2h, i2h_sl);
      k_i2fb<<<NB * 16, 256, 0, stream>>>(xt0, Afi, i2f_sl);
    }
    int ti = fits ? t : 0;
    const __bf16* hb = (t == 0) ? hzb : ((t & 1) ? hbufA : hbufB);
    __bf16* hbc = (t & 1) ? hbufB : hbufA;
    const float* hpf = (t == 0) ? out : out + (ll)(t - 1) * NF * HWSZ;

    k_h2f5<<<NB * 64 * 2, 256, 0, stream>>>(hb, Afh, b_i2f, b_h2f,
                                            i2f_sl + (ll)ti * I2F_T, f1buf);
    k_fwr2<<<NB * 64 * 2, 256, 0, stream>>>(f1buf, Afl, b_flow, hb, Aret, b_ret,
                                            i2h_sl + (ll)ti * I2H_T, hpf,
                                            (t == 0) ? 1 : 0,
                                            out + (ll)t * NF * HWSZ, osb, hbc);
  }
}